// Round 4
// baseline (355.898 us; speedup 1.0000x reference)
//
#include <hip/hip_runtime.h>
#include <math.h>

// ---------------------------------------------------------------------------
// PatientDistillation: three losses.
//  out[0] = train_loss (CE over s_logits/labels)
//  out[1] = soft_loss  (KL(batchmean) at temperature T, * T^2)
//  out[2] = distill_loss (sum over rows of k smallest same-label sq dists / D)
//
// dot[i][j] = sf_i . tf_j as bf16 MFMA split-K GEMM. R3 lesson: GEMM is
// in-flight-bytes limited (1.5 KB/CU -> 2.4 TB/s); tail's serial z-reduce of
// 50 MB was ~200 us. R4: depth-2 register prefetch (16 loads in flight/wave,
// register loads survive barriers), BK=64 (half the barriers), LDS column-
// group swizzle (frag-read banks -> 2-way free), parallel two-stage reduce.
// ---------------------------------------------------------------------------

#define BM 128
#define BN 128
#define BK 64          // two 32-wide halves per k-iteration
#define LPITCH 72      // bf16 elems per LDS row: 144 B, 16B-aligned groups
#define NS 8           // reduction slices for part -> part2

typedef __attribute__((ext_vector_type(8))) short short8;   // 8 bf16 = 4 VGPR
typedef __attribute__((ext_vector_type(4))) float f32x4;

__device__ inline unsigned pack_bf16(float a, float b) {
    // round-to-nearest-even f32 -> bf16, packed pair
    unsigned ua = __float_as_uint(a), ub = __float_as_uint(b);
    ua = (ua + 0x7fffu + ((ua >> 16) & 1u)) >> 16;
    ub = (ub + 0x7fffu + ((ub >> 16) & 1u)) >> 16;
    return (ua & 0xffffu) | (ub << 16);
}

// ---------------- MFMA GEMM: dot partials + norm partials (no atomics) -----
// grid (B/128, B/128, gz); 256 threads = 4 waves; wave owns a 64x64 quadrant
// as 4x4 tiles of 16x16x32 bf16 MFMA. Depth-2 software pipeline: each 32-wide
// half-tile's loads are issued ~1 full iteration before their LDS staging.
// LDS swizzle: column-group g (8 bf16 each) stored at g' = (g + 2*row) & 7;
// frag-read word0 banks become 4*((3r+q)&7) -> 2-way aliasing (free).
__global__ __launch_bounds__(256) void gemm_dot_kernel(const float* __restrict__ S,
                                                       const float* __restrict__ T,
                                                       float* __restrict__ part,   // [gz][B*B]
                                                       float* __restrict__ spart,  // [gz][B]
                                                       float* __restrict__ tpart,  // [gz][B]
                                                       int B, int K, int KC) {
    __shared__ __align__(16) unsigned short As[BM * LPITCH];
    __shared__ __align__(16) unsigned short Bs[BN * LPITCH];

    const int tid  = threadIdx.x;
    const int i0   = blockIdx.x * BM;
    const int j0   = blockIdx.y * BN;
    const int bz   = blockIdx.z;
    const int kbeg = bz * KC;
    const int kend = kbeg + KC;       // KC % BK == 0 guaranteed by launcher

    const int lane = tid & 63;
    const int wid  = tid >> 6;
    const int wm   = wid >> 1;
    const int wn   = wid & 1;
    const int l15  = lane & 15;
    const int quad = lane >> 4;

    // staging coords (per 32-wide half): row = l*32 + tid>>3, 8 threads/row
    const int kq  = tid & 7;
    const int kq4 = kq * 4;
    int rowl[4];
    bool vi[4], vj[4];
    const float* pS[4];
    const float* pT[4];
    int woff[4][2];   // swizzled LDS elem offset per (l, half)
    #pragma unroll
    for (int l = 0; l < 4; ++l) {
        rowl[l] = l * 32 + (tid >> 3);
        int gi = i0 + rowl[l];
        int gj = j0 + rowl[l];
        vi[l] = gi < B;
        vj[l] = gj < B;
        if (gi >= B) gi = B - 1;   // clamp: harmless duplicate loads
        if (gj >= B) gj = B - 1;
        pS[l] = S + (size_t)gi * K + kq4;
        pT[l] = T + (size_t)gj * K + kq4;
        #pragma unroll
        for (int h = 0; h < 2; ++h) {
            const int g  = h * 4 + (kq >> 1);                 // column group 0..7
            const int gp = (g + 2 * (rowl[l] & 7)) & 7;       // swizzled
            woff[l][h] = rowl[l] * LPITCH + gp * 8 + (kq & 1) * 4;
        }
    }
    // frag-read column offsets (swizzled), independent of tile index mi/ni
    int coff[2];
    #pragma unroll
    for (int h = 0; h < 2; ++h)
        coff[h] = ((h * 4 + quad + 2 * (l15 & 7)) & 7) * 8;
    int arow[4], brow[4];
    #pragma unroll
    for (int t = 0; t < 4; ++t) {
        arow[t] = (wm * 64 + t * 16 + l15) * LPITCH;
        brow[t] = (wn * 64 + t * 16 + l15) * LPITCH;
    }

    f32x4 acc[4][4] = {};
    float pn_s[4] = {0.f, 0.f, 0.f, 0.f};
    float pn_t[4] = {0.f, 0.f, 0.f, 0.f};

    // depth-2 prefetch buffers: half0 and half1 of the current iteration
    float4 sv0[4], tv0[4], sv1[4], tv1[4];
    #pragma unroll
    for (int l = 0; l < 4; ++l) {
        sv0[l] = *(const float4*)(pS[l] + kbeg);
        tv0[l] = *(const float4*)(pT[l] + kbeg);
        sv1[l] = *(const float4*)(pS[l] + kbeg + 32);
        tv1[l] = *(const float4*)(pT[l] + kbeg + 32);
    }

    for (int kb = kbeg; kb < kend; kb += BK) {
        __syncthreads();   // prev iter's frag reads done before LDS overwrite
        // ---- stage half 0, then immediately re-issue its loads for iter+1
        #pragma unroll
        for (int l = 0; l < 4; ++l) {
            float4 s = sv0[l], t = tv0[l];
            pn_s[l] += s.x * s.x + s.y * s.y + s.z * s.z + s.w * s.w;
            pn_t[l] += t.x * t.x + t.y * t.y + t.z * t.z + t.w * t.w;
            *(uint2*)&As[woff[l][0]] = make_uint2(pack_bf16(s.x, s.y), pack_bf16(s.z, s.w));
            *(uint2*)&Bs[woff[l][0]] = make_uint2(pack_bf16(t.x, t.y), pack_bf16(t.z, t.w));
        }
        {
            const int kn = (kb + BK < kend) ? (kb + BK) : kbeg;
            #pragma unroll
            for (int l = 0; l < 4; ++l) {
                sv0[l] = *(const float4*)(pS[l] + kn);
                tv0[l] = *(const float4*)(pT[l] + kn);
            }
        }
        // ---- stage half 1, re-issue its loads for iter+1
        #pragma unroll
        for (int l = 0; l < 4; ++l) {
            float4 s = sv1[l], t = tv1[l];
            pn_s[l] += s.x * s.x + s.y * s.y + s.z * s.z + s.w * s.w;
            pn_t[l] += t.x * t.x + t.y * t.y + t.z * t.z + t.w * t.w;
            *(uint2*)&As[woff[l][1]] = make_uint2(pack_bf16(s.x, s.y), pack_bf16(s.z, s.w));
            *(uint2*)&Bs[woff[l][1]] = make_uint2(pack_bf16(t.x, t.y), pack_bf16(t.z, t.w));
        }
        {
            const int kn = (kb + BK + 32 < kend) ? (kb + BK + 32) : kbeg;
            #pragma unroll
            for (int l = 0; l < 4; ++l) {
                sv1[l] = *(const float4*)(pS[l] + kn);
                tv1[l] = *(const float4*)(pT[l] + kn);
            }
        }
        __syncthreads();

        // ---- MFMA over both 32-wide phases
        #pragma unroll
        for (int h = 0; h < 2; ++h) {
            short8 af[4], bf[4];
            #pragma unroll
            for (int mi = 0; mi < 4; ++mi)
                af[mi] = *(const short8*)&As[arow[mi] + coff[h]];
            #pragma unroll
            for (int ni = 0; ni < 4; ++ni)
                bf[ni] = *(const short8*)&Bs[brow[ni] + coff[h]];
            #pragma unroll
            for (int mi = 0; mi < 4; ++mi)
                #pragma unroll
                for (int ni = 0; ni < 4; ++ni)
                    acc[mi][ni] = __builtin_amdgcn_mfma_f32_16x16x32_bf16(
                        af[mi], bf[ni], acc[mi][ni], 0, 0, 0);
        }
    }

    // ---- dot partials: plain stores ----
    // C/D layout (16x16x32): col = lane&15, row = (lane>>4)*4 + reg
    float* outp = part + (size_t)bz * B * B;
    #pragma unroll
    for (int mi = 0; mi < 4; ++mi) {
        #pragma unroll
        for (int ni = 0; ni < 4; ++ni) {
            #pragma unroll
            for (int r = 0; r < 4; ++r) {
                const int ig = i0 + wm * 64 + mi * 16 + quad * 4 + r;
                const int jg = j0 + wn * 64 + ni * 16 + l15;
                if (ig < B && jg < B)
                    outp[(size_t)ig * B + jg] = acc[mi][ni][r];
            }
        }
    }

    // ---- norm partials: 8-lane shuffle reduce, one plain store per row ----
    if (blockIdx.y == 0) {
        #pragma unroll
        for (int l = 0; l < 4; ++l) {
            float v = pn_s[l];
            v += __shfl_xor(v, 1, 64);
            v += __shfl_xor(v, 2, 64);
            v += __shfl_xor(v, 4, 64);
            if (kq == 0 && vi[l]) spart[(size_t)bz * B + i0 + rowl[l]] = v;
        }
    }
    if (blockIdx.x == 0) {
        #pragma unroll
        for (int l = 0; l < 4; ++l) {
            float v = pn_t[l];
            v += __shfl_xor(v, 1, 64);
            v += __shfl_xor(v, 2, 64);
            v += __shfl_xor(v, 4, 64);
            if (kq == 0 && vj[l]) tpart[(size_t)bz * B + j0 + rowl[l]] = v;
        }
    }
}

// ---------------- stage-1 parallel reduce: part -> NS slice planes ---------
// grid (BB/256, NS): 2048 blocks, fully coalesced, ~8 blocks/CU.
__global__ __launch_bounds__(256) void reduce_kernel(const float* __restrict__ part,
                                                     float* __restrict__ part2,
                                                     int n, int gz) {
    const int idx   = blockIdx.x * 256 + threadIdx.x;
    const int slice = blockIdx.y;
    if (idx >= n) return;
    float s = 0.f;
    for (int z = slice; z < gz; z += NS)
        s += part[(size_t)z * n + idx];
    part2[(size_t)slice * n + idx] = s;
}

// ---------------- norm partial reduce: block 0 -> s_nrm, block 1 -> t_nrm --
__global__ __launch_bounds__(256) void norm_reduce_kernel(const float* __restrict__ spart,
                                                          const float* __restrict__ tpart,
                                                          float* __restrict__ s_nrm,
                                                          float* __restrict__ t_nrm,
                                                          int B, int gz) {
    const int r = threadIdx.x;
    if (r >= B) return;
    const float* src = blockIdx.x ? tpart : spart;
    float s = 0.f;
    for (int z = 0; z < gz; ++z) s += src[(size_t)z * B + r];
    if (blockIdx.x) t_nrm[r] = s; else s_nrm[r] = s;
}

// ---------------- tail: finish reduce + topk + CE/KL -----------------------
// grid = B blocks; block i handles row i (reads only NS slice values per j).
// Last block to finish also computes CE/KL and writes out[0..2].
__global__ __launch_bounds__(256) void tail_kernel(const float* __restrict__ part2,
                                                   const float* __restrict__ s_nrm,
                                                   const float* __restrict__ t_nrm,
                                                   const float* __restrict__ t_logits,
                                                   const float* __restrict__ s_logits,
                                                   const int* __restrict__ labels,
                                                   const int* __restrict__ kp,
                                                   const int* __restrict__ tp,
                                                   float* __restrict__ rowsum,
                                                   int* __restrict__ counter,
                                                   float* __restrict__ out,
                                                   int B, int K, int NL) {
    const int i   = blockIdx.x;
    const int tid = threadIdx.x;
    const size_t BB = (size_t)B * B;

    __shared__ float svals[256];
    __shared__ float rv[256];
    __shared__ int   ri[256];
    __shared__ int   lastf;

    float v = INFINITY;
    if (tid < B && labels[i] == labels[tid]) {
        float dt = 0.f;
        #pragma unroll
        for (int s = 0; s < NS; ++s)
            dt += part2[(size_t)s * BB + (size_t)i * B + tid];
        v = fmaxf(s_nrm[i] + t_nrm[tid] - 2.0f * dt, 0.0f);
    }
    svals[tid] = v;
    __syncthreads();

    const int k = kp[0];
    float sum = 0.0f;
    for (int it = 0; it < k; ++it) {
        rv[tid] = svals[tid];
        ri[tid] = tid;
        __syncthreads();
        #pragma unroll
        for (int s = 128; s > 0; s >>= 1) {
            if (tid < s) {
                if (rv[tid + s] < rv[tid]) { rv[tid] = rv[tid + s]; ri[tid] = ri[tid + s]; }
            }
            __syncthreads();
        }
        if (tid == 0) {
            if (rv[0] < 3.0e38f) sum += rv[0];
            svals[ri[0]] = INFINITY;
        }
        __syncthreads();
    }

    if (tid == 0) {
        rowsum[i] = sum;
        __threadfence();
        lastf = (atomicAdd(counter, 1) == B - 1) ? 1 : 0;
    }
    __syncthreads();
    if (!lastf) return;

    // ---- last block: finalize all three losses ----
    __threadfence();
    const float Tv = (float)tp[0];
    float rs = (tid < B) ? rowsum[tid] : 0.f;
    float ce = 0.0f, kl = 0.0f;
    for (int s = tid; s < B; s += 256) {
        const float* sl = s_logits + (size_t)s * NL;
        const float* tl = t_logits + (size_t)s * NL;
        float mx = -INFINITY;
        for (int c = 0; c < NL; ++c) mx = fmaxf(mx, sl[c]);
        float se = 0.0f;
        for (int c = 0; c < NL; ++c) se += expf(sl[c] - mx);
        ce += logf(se) + mx - sl[labels[s]];

        float mxs = -INFINITY, mxt = -INFINITY;
        for (int c = 0; c < NL; ++c) {
            mxs = fmaxf(mxs, sl[c] / Tv);
            mxt = fmaxf(mxt, tl[c] / Tv);
        }
        float ses = 0.0f, set = 0.0f;
        for (int c = 0; c < NL; ++c) {
            ses += expf(sl[c] / Tv - mxs);
            set += expf(tl[c] / Tv - mxt);
        }
        float lses = logf(ses) + mxs;
        float lset = logf(set) + mxt;
        for (int c = 0; c < NL; ++c) {
            float lst = tl[c] / Tv - lset;
            float ls  = sl[c] / Tv - lses;
            kl += expf(lst) * (lst - ls);
        }
    }
    #pragma unroll
    for (int off = 32; off > 0; off >>= 1) {
        ce += __shfl_down(ce, off, 64);
        kl += __shfl_down(kl, off, 64);
        rs += __shfl_down(rs, off, 64);
    }
    __shared__ float wce[4], wkl[4], wrs[4];
    if ((tid & 63) == 0) { wce[tid >> 6] = ce; wkl[tid >> 6] = kl; wrs[tid >> 6] = rs; }
    __syncthreads();
    if (tid == 0) {
        out[0] = (wce[0] + wce[1] + wce[2] + wce[3]) / (float)B;
        out[1] = (wkl[0] + wkl[1] + wkl[2] + wkl[3]) / (float)B * Tv * Tv;
        out[2] = (wrs[0] + wrs[1] + wrs[2] + wrs[3]) / (float)K;
    }
}

// ---------------------------------------------------------------------------
extern "C" void kernel_launch(void* const* d_in, const int* in_sizes, int n_in,
                              void* d_out, int out_size, void* d_ws, size_t ws_size,
                              hipStream_t stream) {
    const float* t_logits = (const float*)d_in[0];
    const float* s_logits = (const float*)d_in[1];
    const float* t_feat   = (const float*)d_in[2];
    const float* s_feat   = (const float*)d_in[3];
    const int*   labels   = (const int*)d_in[4];
    const int*   kp       = (const int*)d_in[5];
    const int*   tp       = (const int*)d_in[6];
    float* out = (float*)d_out;

    const int B  = in_sizes[4];          // 256
    const int NL = in_sizes[0] / B;      // 2
    const int K  = in_sizes[2] / B;      // S*H = 98304
    const size_t BB = (size_t)B * B;

    // split-K: largest gz (4 blocks/CU at 256) with K % (gz*BK) == 0 and all
    // workspace buffers fitting in ws.
    const size_t avail = ws_size / 4;
    const int cands[] = {256, 192, 128, 96, 64, 48, 32, 24, 16, 12, 8, 6, 4, 3, 2, 1};
    int gz = 1;
    for (int ci = 0; ci < 16; ++ci) {
        const int g = cands[ci];
        if (K % (g * BK) != 0) continue;
        const size_t need = (size_t)g * BB + (size_t)NS * BB
                          + 2 * (size_t)g * B + 3 * (size_t)B + 1;
        if (need <= avail) { gz = g; break; }
    }
    const int KC = K / gz;

    float* ws      = (float*)d_ws;
    float* part    = ws;                          // gz * B*B
    float* part2   = part + (size_t)gz * BB;      // NS * B*B
    float* spart   = part2 + (size_t)NS * BB;     // gz * B
    float* tpart   = spart + (size_t)gz * B;      // gz * B
    float* s_nrm   = tpart + (size_t)gz * B;      // B
    float* t_nrm   = s_nrm + B;                   // B
    float* rowsum  = t_nrm + B;                   // B
    int*   counter = (int*)(rowsum + B);          // 1

    hipMemsetAsync(counter, 0, sizeof(int), stream);

    dim3 grid((B + BM - 1) / BM, (B + BN - 1) / BN, gz);
    gemm_dot_kernel<<<grid, 256, 0, stream>>>(s_feat, t_feat, part, spart, tpart,
                                              B, K, KC);

    dim3 grid2((unsigned)((BB + 255) / 256), NS);
    reduce_kernel<<<grid2, 256, 0, stream>>>(part, part2, (int)BB, gz);

    norm_reduce_kernel<<<2, 256, 0, stream>>>(spart, tpart, s_nrm, t_nrm, B, gz);

    tail_kernel<<<B, 256, 0, stream>>>(part2, s_nrm, t_nrm, t_logits, s_logits,
                                       labels, kp, tp, rowsum, counter, out,
                                       B, K, NL);
}

// Round 5
// 277.133 us; speedup vs baseline: 1.2842x; 1.2842x over previous
//
#include <hip/hip_runtime.h>
#include <math.h>

// ---------------------------------------------------------------------------
// PatientDistillation: three losses.
//  out[0] = train_loss (CE over s_logits/labels)
//  out[1] = soft_loss  (KL(batchmean) at temperature T, * T^2)
//  out[2] = distill_loss (sum over rows of k smallest same-label sq dists / D)
//
// dot[i][j] = sf_i . tf_j: split-K MFMA GEMM. R4 lesson: register prefetch is
// in-flight-byte capped at ~4 KB/CU -> 2.7 TB/s. R5: global_load_lds async DMA
// stages f32 tiles (no VGPR cost -> ~32 KB in flight per block), XOR-swizzled
// 16B groups so frag ds_read_b128s are 2-way bank-aliased (free), f32->bf16
// truncation-pack at frag read (2 VALU/pack; bias ~0.03 abs on out[2] vs
// threshold ~50). Norms = row sums of squares of the staged LDS tiles
// (swizzle-invariant). No device atomics in the GEMM (R2 lesson).
// ---------------------------------------------------------------------------

#define BM 128
#define BN 128
#define BKF 32        // f32 k-elements per iteration; row = 128 B = 8 groups
#define NS 8          // reduction slices

typedef __attribute__((ext_vector_type(8))) short short8;   // 8 bf16 = 4 VGPR
typedef __attribute__((ext_vector_type(4))) float f32x4;

__device__ inline void async16(const float* g, float* l) {
    // async global->LDS DMA, 16 B per lane; LDS dest = uniform base + lane*16
    __builtin_amdgcn_global_load_lds(
        (const __attribute__((address_space(1))) void*)g,
        (__attribute__((address_space(3))) void*)l,
        16, 0, 0);
}

__device__ inline unsigned pack_trunc(float a, float b) {
    // f32 -> bf16 truncation, packed pair (2 VALU: lshr + and_or)
    return (__float_as_uint(a) >> 16) | (__float_as_uint(b) & 0xffff0000u);
}

union U8 { short8 v; unsigned u[4]; };

// ---------------- MFMA GEMM: dot partials + norm partials ------------------
// grid (B/128, B/128, gz); 256 threads = 4 waves; wave owns a 64x64 quadrant
// as 4x4 tiles of 16x16x32 bf16 MFMA (one MFMA consumes the full BKF=32).
// Staging: 32 chunk-jobs of 1 KB (8 rows x 128 B), 8 per wave, via async16.
// Swizzle: data group g of row r stored at position g ^ (r&7).
__global__ __launch_bounds__(256) void gemm_dot_kernel(const float* __restrict__ S,
                                                       const float* __restrict__ T,
                                                       float* __restrict__ part,   // [gz][B*B]
                                                       float* __restrict__ spart,  // [gz][B]
                                                       float* __restrict__ tpart,  // [gz][B]
                                                       int B, int K, int KC) {
    __shared__ __align__(16) float As[BM * BKF];   // 16 KB
    __shared__ __align__(16) float Bs[BN * BKF];   // 16 KB

    const int tid  = threadIdx.x;
    const int i0   = blockIdx.x * BM;
    const int j0   = blockIdx.y * BN;
    const int bz   = blockIdx.z;
    const int kbeg = bz * KC;
    const int kend = kbeg + KC;      // KC % BKF == 0 guaranteed by launcher

    const int lane = tid & 63;
    const int wid  = tid >> 6;
    const int wm   = wid >> 1;
    const int wn   = wid & 1;
    const int l15  = lane & 15;
    const int quad = lane >> 4;

    // ---- staging job setup: wave wid owns chunks 4*wid..4*wid+3 (A and B)
    // lane = rl*8 + p; chunk c covers rows 8c..8c+7; stored group p holds
    // data group g = p ^ (row&7)  ->  source col = kb + g*4 floats.
    const int rl = lane >> 3;
    const int p  = lane & 7;
    const float* srcA[4];
    const float* srcB[4];
    float* dstA[4];
    float* dstB[4];
    #pragma unroll
    for (int j = 0; j < 4; ++j) {
        const int c   = wid * 4 + j;
        const int row = c * 8 + rl;
        const int g   = p ^ (row & 7);
        int gi = i0 + row; if (gi >= B) gi = B - 1;   // harmless duplicate
        int gj = j0 + row; if (gj >= B) gj = B - 1;
        srcA[j] = S + (size_t)gi * K + kbeg + g * 4;
        srcB[j] = T + (size_t)gj * K + kbeg + g * 4;
        dstA[j] = &As[c * 256];   // wave-uniform (c uniform per wave)
        dstB[j] = &Bs[c * 256];
    }

    // ---- frag read offsets (float indices); data group 2q of row r sits at
    // position (2q)^(r&7), group 2q+1 at that ^1.
    int aoff[4], boff[4];
    #pragma unroll
    for (int t = 0; t < 4; ++t) {
        const int ra = wm * 64 + t * 16 + l15;
        aoff[t] = ra * BKF + (((2 * quad) ^ (ra & 7)) * 4);
        const int rb = wn * 64 + t * 16 + l15;
        boff[t] = rb * BKF + (((2 * quad) ^ (rb & 7)) * 4);
    }
    // position^1 flips float offset by +/-4: precompute XOR of float index
    // pos*4 -> (pos^1)*4 == (pos*4) ^ 4.

    const bool doS = (blockIdx.y == 0);
    const bool doT = (blockIdx.x == 0);
    const int  rn  = tid >> 1;       // norm row 0..127
    const int  hn  = tid & 1;        // half: groups hn*4..hn*4+3 (rotated)

    f32x4 acc[4][4] = {};
    float pns = 0.f, pnt = 0.f;

    for (int kb = kbeg; kb < kend; kb += BKF) {
        __syncthreads();   // prev iter's LDS reads complete before overwrite
        #pragma unroll
        for (int j = 0; j < 4; ++j) {
            async16(srcA[j], dstA[j]);
            async16(srcB[j], dstB[j]);
            srcA[j] += BKF;
            srcB[j] += BKF;
        }
        __syncthreads();   // drains vmcnt -> staged data visible

        // ---- norms from staged f32 tiles (row sums, swizzle-invariant)
        if (doS) {
            #pragma unroll
            for (int j = 0; j < 4; ++j) {
                const int pos = hn * 4 + ((j + rn) & 3);
                f32x4 v = *(const f32x4*)&As[rn * BKF + pos * 4];
                pns += v.x * v.x + v.y * v.y + v.z * v.z + v.w * v.w;
            }
        }
        if (doT) {
            #pragma unroll
            for (int j = 0; j < 4; ++j) {
                const int pos = hn * 4 + ((j + rn) & 3);
                f32x4 v = *(const f32x4*)&Bs[rn * BKF + pos * 4];
                pnt += v.x * v.x + v.y * v.y + v.z * v.z + v.w * v.w;
            }
        }

        // ---- frags: two b128 f32 reads + truncation pack -> bf16 short8
        short8 af[4], bf[4];
        #pragma unroll
        for (int t = 0; t < 4; ++t) {
            f32x4 va = *(const f32x4*)&As[aoff[t]];
            f32x4 vb = *(const f32x4*)&As[aoff[t] ^ 4];
            U8 u;
            u.u[0] = pack_trunc(va.x, va.y);
            u.u[1] = pack_trunc(va.z, va.w);
            u.u[2] = pack_trunc(vb.x, vb.y);
            u.u[3] = pack_trunc(vb.z, vb.w);
            af[t] = u.v;
        }
        #pragma unroll
        for (int t = 0; t < 4; ++t) {
            f32x4 va = *(const f32x4*)&Bs[boff[t]];
            f32x4 vb = *(const f32x4*)&Bs[boff[t] ^ 4];
            U8 u;
            u.u[0] = pack_trunc(va.x, va.y);
            u.u[1] = pack_trunc(va.z, va.w);
            u.u[2] = pack_trunc(vb.x, vb.y);
            u.u[3] = pack_trunc(vb.z, vb.w);
            bf[t] = u.v;
        }
        #pragma unroll
        for (int mi = 0; mi < 4; ++mi)
            #pragma unroll
            for (int ni = 0; ni < 4; ++ni)
                acc[mi][ni] = __builtin_amdgcn_mfma_f32_16x16x32_bf16(
                    af[mi], bf[ni], acc[mi][ni], 0, 0, 0);
    }

    // ---- dot partials: plain stores ----
    // C/D layout (16x16x32): col = lane&15, row = (lane>>4)*4 + reg
    float* outp = part + (size_t)bz * B * B;
    #pragma unroll
    for (int mi = 0; mi < 4; ++mi) {
        #pragma unroll
        for (int ni = 0; ni < 4; ++ni) {
            #pragma unroll
            for (int r = 0; r < 4; ++r) {
                const int ig = i0 + wm * 64 + mi * 16 + quad * 4 + r;
                const int jg = j0 + wn * 64 + ni * 16 + l15;
                if (ig < B && jg < B)
                    outp[(size_t)ig * B + jg] = acc[mi][ni][r];
            }
        }
    }

    // ---- norm partials: pair-reduce (threads 2rn, 2rn+1), one store/row ----
    if (doS) {
        float v = pns + __shfl_xor(pns, 1, 64);
        if (hn == 0 && i0 + rn < B) spart[(size_t)bz * B + i0 + rn] = v;
    }
    if (doT) {
        float v = pnt + __shfl_xor(pnt, 1, 64);
        if (hn == 0 && j0 + rn < B) tpart[(size_t)bz * B + j0 + rn] = v;
    }
}

// ---------------- stage-1 parallel reduce: part -> NS slices; + norms ------
// grid (BB/256 + 1, NS). Last x-block reduces the norm partials.
__global__ __launch_bounds__(256) void reduce_kernel(const float* __restrict__ part,
                                                     const float* __restrict__ spart,
                                                     const float* __restrict__ tpart,
                                                     float* __restrict__ part2,
                                                     float* __restrict__ snorm2,
                                                     float* __restrict__ tnorm2,
                                                     int n, int B, int gz) {
    const int s  = blockIdx.y;
    const int bx = blockIdx.x;
    const int t  = threadIdx.x;
    if ((int)bx * 256 < n) {
        const int idx = bx * 256 + t;
        if (idx < n) {
            float a = 0.f;
            for (int z = s; z < gz; z += NS)
                a += part[(size_t)z * n + idx];
            part2[(size_t)s * n + idx] = a;
        }
    } else {
        if (t < B) {
            float a = 0.f, b = 0.f;
            for (int z = s; z < gz; z += NS) {
                a += spart[(size_t)z * B + t];
                b += tpart[(size_t)z * B + t];
            }
            snorm2[s * B + t] = a;
            tnorm2[s * B + t] = b;
        }
    }
}

// ---------------- tail: finish reduce + topk + CE/KL -----------------------
// grid = B blocks; block i handles row i. Last block finalizes out[0..2].
__global__ __launch_bounds__(256) void tail_kernel(const float* __restrict__ part2,
                                                   const float* __restrict__ snorm2,
                                                   const float* __restrict__ tnorm2,
                                                   const float* __restrict__ t_logits,
                                                   const float* __restrict__ s_logits,
                                                   const int* __restrict__ labels,
                                                   const int* __restrict__ kp,
                                                   const int* __restrict__ tp,
                                                   float* __restrict__ rowsum,
                                                   int* __restrict__ counter,
                                                   float* __restrict__ out,
                                                   int B, int K, int NL) {
    const int i   = blockIdx.x;
    const int tid = threadIdx.x;
    const size_t BB = (size_t)B * B;

    __shared__ float svals[256];
    __shared__ float rv[256];
    __shared__ int   ri[256];
    __shared__ int   lastf;

    float v = INFINITY;
    if (tid < B && labels[i] == labels[tid]) {
        float dt = 0.f, sn = 0.f, tn = 0.f;
        #pragma unroll
        for (int s = 0; s < NS; ++s) {
            dt += part2[(size_t)s * BB + (size_t)i * B + tid];
            sn += snorm2[s * B + i];
            tn += tnorm2[s * B + tid];
        }
        v = fmaxf(sn + tn - 2.0f * dt, 0.0f);
    }
    svals[tid] = v;
    __syncthreads();

    const int k = kp[0];
    float sum = 0.0f;
    for (int it = 0; it < k; ++it) {
        rv[tid] = svals[tid];
        ri[tid] = tid;
        __syncthreads();
        #pragma unroll
        for (int s = 128; s > 0; s >>= 1) {
            if (tid < s) {
                if (rv[tid + s] < rv[tid]) { rv[tid] = rv[tid + s]; ri[tid] = ri[tid + s]; }
            }
            __syncthreads();
        }
        if (tid == 0) {
            if (rv[0] < 3.0e38f) sum += rv[0];
            svals[ri[0]] = INFINITY;
        }
        __syncthreads();
    }

    if (tid == 0) {
        rowsum[i] = sum;
        __threadfence();
        lastf = (atomicAdd(counter, 1) == B - 1) ? 1 : 0;
    }
    __syncthreads();
    if (!lastf) return;

    // ---- last block: finalize all three losses ----
    __threadfence();
    const float Tv = (float)tp[0];
    float rs = (tid < B) ? rowsum[tid] : 0.f;
    float ce = 0.0f, kl = 0.0f;
    for (int s = tid; s < B; s += 256) {
        const float* sl = s_logits + (size_t)s * NL;
        const float* tl = t_logits + (size_t)s * NL;
        float mx = -INFINITY;
        for (int c = 0; c < NL; ++c) mx = fmaxf(mx, sl[c]);
        float se = 0.0f;
        for (int c = 0; c < NL; ++c) se += expf(sl[c] - mx);
        ce += logf(se) + mx - sl[labels[s]];

        float mxs = -INFINITY, mxt = -INFINITY;
        for (int c = 0; c < NL; ++c) {
            mxs = fmaxf(mxs, sl[c] / Tv);
            mxt = fmaxf(mxt, tl[c] / Tv);
        }
        float ses = 0.0f, set = 0.0f;
        for (int c = 0; c < NL; ++c) {
            ses += expf(sl[c] / Tv - mxs);
            set += expf(tl[c] / Tv - mxt);
        }
        float lses = logf(ses) + mxs;
        float lset = logf(set) + mxt;
        for (int c = 0; c < NL; ++c) {
            float lst = tl[c] / Tv - lset;
            float ls  = sl[c] / Tv - lses;
            kl += expf(lst) * (lst - ls);
        }
    }
    #pragma unroll
    for (int off = 32; off > 0; off >>= 1) {
        ce += __shfl_down(ce, off, 64);
        kl += __shfl_down(kl, off, 64);
        rs += __shfl_down(rs, off, 64);
    }
    __shared__ float wce[4], wkl[4], wrs[4];
    if ((tid & 63) == 0) { wce[tid >> 6] = ce; wkl[tid >> 6] = kl; wrs[tid >> 6] = rs; }
    __syncthreads();
    if (tid == 0) {
        out[0] = (wce[0] + wce[1] + wce[2] + wce[3]) / (float)B;
        out[1] = (wkl[0] + wkl[1] + wkl[2] + wkl[3]) / (float)B * Tv * Tv;
        out[2] = (wrs[0] + wrs[1] + wrs[2] + wrs[3]) / (float)K;
    }
}

// ---------------------------------------------------------------------------
extern "C" void kernel_launch(void* const* d_in, const int* in_sizes, int n_in,
                              void* d_out, int out_size, void* d_ws, size_t ws_size,
                              hipStream_t stream) {
    const float* t_logits = (const float*)d_in[0];
    const float* s_logits = (const float*)d_in[1];
    const float* t_feat   = (const float*)d_in[2];
    const float* s_feat   = (const float*)d_in[3];
    const int*   labels   = (const int*)d_in[4];
    const int*   kp       = (const int*)d_in[5];
    const int*   tp       = (const int*)d_in[6];
    float* out = (float*)d_out;

    const int B  = in_sizes[4];          // 256
    const int NL = in_sizes[0] / B;      // 2
    const int K  = in_sizes[2] / B;      // S*H = 98304
    const size_t BB = (size_t)B * B;

    // split-K: prefer gz=192 (3 blocks/CU, minimal partial traffic; async DMA
    // makes in-flight independent of occupancy). K % (gz*BKF) == 0 required.
    const size_t avail = ws_size / 4;
    const int cands[] = {192, 256, 128, 96, 64, 48, 32, 24, 16, 12, 8, 6, 4, 3, 2, 1};
    int gz = 1;
    for (int ci = 0; ci < 16; ++ci) {
        const int g = cands[ci];
        if (K % (g * BKF) != 0) continue;
        const size_t need = (size_t)g * BB + (size_t)NS * BB
                          + 2 * (size_t)g * B + 2 * (size_t)NS * B + B + 1;
        if (need <= avail) { gz = g; break; }
    }
    const int KC = K / gz;

    float* ws      = (float*)d_ws;
    float* part    = ws;                          // gz * B*B
    float* part2   = part + (size_t)gz * BB;      // NS * B*B
    float* spart   = part2 + (size_t)NS * BB;     // gz * B
    float* tpart   = spart + (size_t)gz * B;      // gz * B
    float* snorm2  = tpart + (size_t)gz * B;      // NS * B
    float* tnorm2  = snorm2 + (size_t)NS * B;     // NS * B
    float* rowsum  = tnorm2 + (size_t)NS * B;     // B
    int*   counter = (int*)(rowsum + B);          // 1

    hipMemsetAsync(counter, 0, sizeof(int), stream);

    dim3 grid((B + BM - 1) / BM, (B + BN - 1) / BN, gz);
    gemm_dot_kernel<<<grid, 256, 0, stream>>>(s_feat, t_feat, part, spart, tpart,
                                              B, K, KC);

    dim3 grid2((unsigned)(BB / 256 + 1), NS);
    reduce_kernel<<<grid2, 256, 0, stream>>>(part, spart, tpart, part2,
                                             snorm2, tnorm2, (int)BB, B, gz);

    tail_kernel<<<B, 256, 0, stream>>>(part2, snorm2, tnorm2, t_logits, s_logits,
                                       labels, kp, tp, rowsum, counter, out,
                                       B, K, NL);
}

// Round 6
// 272.350 us; speedup vs baseline: 1.3068x; 1.0176x over previous
//
#include <hip/hip_runtime.h>
#include <math.h>

// ---------------------------------------------------------------------------
// PatientDistillation: three losses.
//  out[0] = train_loss (CE over s_logits/labels)
//  out[1] = soft_loss  (KL(batchmean) at temperature T, * T^2)
//  out[2] = distill_loss (sum over rows of k smallest same-label sq dists / D)
//
// R5 lesson: issue-then-immediately-drain async DMA = serial phases (5000
// cyc/iter vs 3200 transfer). R6: LDS double-buffer with EARLY issue (DMA
// progresses across the whole compute phase before the next barrier drain),
// and dispatch count 5 -> 2 (residual ~180 us across R1-R5 tracks dispatch
// count, not aux-kernel bytes). No device atomics in the GEMM (R2 lesson).
// ---------------------------------------------------------------------------

#define BM 128
#define BN 128
#define BKF 32          // f32 k-elems per stage; row = 128 B = 8 16B-groups
#define STAGE (BM * BKF)   // floats per matrix per stage (4096)

typedef __attribute__((ext_vector_type(8))) short short8;   // 8 bf16 = 4 VGPR
typedef __attribute__((ext_vector_type(4))) float f32x4;

__device__ inline void async16(const float* g, float* l) {
    // async global->LDS DMA, 16 B/lane; LDS dest = wave-uniform base + lane*16
    __builtin_amdgcn_global_load_lds(
        (const __attribute__((address_space(1))) void*)g,
        (__attribute__((address_space(3))) void*)l,
        16, 0, 0);
}

__device__ inline unsigned pack_trunc(float a, float b) {
    // f32 -> bf16 truncation, packed pair
    return (__float_as_uint(a) >> 16) | (__float_as_uint(b) & 0xffff0000u);
}

union U8 { short8 v; unsigned u[4]; };

// ---------------- MFMA GEMM: dot partials + norm partials ------------------
// grid (B/128, B/128, gz); 256 threads = 4 waves; wave owns a 64x64 quadrant
// as 4x4 tiles of 16x16x32 bf16 MFMA. Double-buffered async staging:
//   sync(drain p) ; issue p^1 ; compute p.
// Swizzle: data group g of row r stored at position g ^ (r&7) (R5-verified).
__global__ __launch_bounds__(256) void gemm_dot_kernel(const float* __restrict__ S,
                                                       const float* __restrict__ T,
                                                       float* __restrict__ part,   // [gz][B*B]
                                                       float* __restrict__ spart,  // [gz][B]
                                                       float* __restrict__ tpart,  // [gz][B]
                                                       int* __restrict__ counter,
                                                       int B, int K, int KC) {
    extern __shared__ __align__(16) float smem[];   // 2 stages x (As|Bs) = 16384 floats

    const int tid  = threadIdx.x;
    const int i0   = blockIdx.x * BM;
    const int j0   = blockIdx.y * BN;
    const int bz   = blockIdx.z;
    const int kbeg = bz * KC;
    const int kend = kbeg + KC;      // KC % BKF == 0 guaranteed by launcher

    if (blockIdx.x == 0 && blockIdx.y == 0 && bz == 0 && tid == 0)
        *counter = 0;                // replaces the memset dispatch

    const int lane = tid & 63;
    const int wid  = tid >> 6;
    const int wm   = wid >> 1;
    const int wn   = wid & 1;
    const int l15  = lane & 15;
    const int quad = lane >> 4;

    // ---- staging jobs: wave wid owns chunks 4*wid..4*wid+3 (A and B).
    // lane = rl*8 + p; chunk c covers rows 8c..8c+7; stored group p holds
    // data group g = p ^ (row&7) -> source col = k + g*4 floats.
    const int rl = lane >> 3;
    const int p  = lane & 7;
    const float* srcA[4];
    const float* srcB[4];
    int dstOff[4];
    #pragma unroll
    for (int j = 0; j < 4; ++j) {
        const int c   = wid * 4 + j;
        const int row = c * 8 + rl;
        const int g   = p ^ (row & 7);
        int gi = i0 + row; if (gi >= B) gi = B - 1;   // harmless duplicate
        int gj = j0 + row; if (gj >= B) gj = B - 1;
        srcA[j] = S + (size_t)gi * K + kbeg + g * 4;
        srcB[j] = T + (size_t)gj * K + kbeg + g * 4;
        dstOff[j] = c * 256;          // wave-uniform within each matrix block
    }

    // ---- frag read offsets (float indices into a stage's As/Bs)
    int aoff[4], boff[4];
    #pragma unroll
    for (int t = 0; t < 4; ++t) {
        const int ra = wm * 64 + t * 16 + l15;
        aoff[t] = ra * BKF + (((2 * quad) ^ (ra & 7)) * 4);
        const int rb = wn * 64 + t * 16 + l15;
        boff[t] = rb * BKF + (((2 * quad) ^ (rb & 7)) * 4);
    }

    const bool doS = (blockIdx.y == 0);
    const bool doT = (blockIdx.x == 0);
    const int  rn  = tid >> 1;       // norm row 0..127
    const int  hn  = tid & 1;

    f32x4 acc[4][4] = {};
    float pns = 0.f, pnt = 0.f;

    // ---- prologue: issue stage 0
    {
        float* As0 = smem;
        float* Bs0 = smem + STAGE;
        #pragma unroll
        for (int j = 0; j < 4; ++j) {
            async16(srcA[j], &As0[dstOff[j]]);
            async16(srcB[j], &Bs0[dstOff[j]]);
            srcA[j] += BKF;
            srcB[j] += BKF;
        }
    }

    int par = 0;
    for (int kb = kbeg; kb < kend; kb += BKF) {
        __syncthreads();   // drains DMA for stage par (vmcnt->0 at barrier)

        // ---- early issue of next stage: progresses across compute phase
        if (kb + BKF < kend) {
            float* Asn = smem + (par ^ 1) * 2 * STAGE;
            float* Bsn = Asn + STAGE;
            #pragma unroll
            for (int j = 0; j < 4; ++j) {
                async16(srcA[j], &Asn[dstOff[j]]);
                async16(srcB[j], &Bsn[dstOff[j]]);
                srcA[j] += BKF;
                srcB[j] += BKF;
            }
        }

        const float* As = smem + par * 2 * STAGE;
        const float* Bs = As + STAGE;

        // ---- norms from staged f32 tiles (row sums, swizzle-invariant)
        if (doS) {
            #pragma unroll
            for (int j = 0; j < 4; ++j) {
                const int pos = hn * 4 + ((j + rn) & 3);
                f32x4 v = *(const f32x4*)&As[rn * BKF + pos * 4];
                pns += v.x * v.x + v.y * v.y + v.z * v.z + v.w * v.w;
            }
        }
        if (doT) {
            #pragma unroll
            for (int j = 0; j < 4; ++j) {
                const int pos = hn * 4 + ((j + rn) & 3);
                f32x4 v = *(const f32x4*)&Bs[rn * BKF + pos * 4];
                pnt += v.x * v.x + v.y * v.y + v.z * v.z + v.w * v.w;
            }
        }

        // ---- frags: two b128 f32 reads + truncation pack -> bf16 short8
        short8 af[4], bf[4];
        #pragma unroll
        for (int t = 0; t < 4; ++t) {
            f32x4 va = *(const f32x4*)&As[aoff[t]];
            f32x4 vb = *(const f32x4*)&As[aoff[t] ^ 4];
            U8 u;
            u.u[0] = pack_trunc(va.x, va.y);
            u.u[1] = pack_trunc(va.z, va.w);
            u.u[2] = pack_trunc(vb.x, vb.y);
            u.u[3] = pack_trunc(vb.z, vb.w);
            af[t] = u.v;
        }
        #pragma unroll
        for (int t = 0; t < 4; ++t) {
            f32x4 va = *(const f32x4*)&Bs[boff[t]];
            f32x4 vb = *(const f32x4*)&Bs[boff[t] ^ 4];
            U8 u;
            u.u[0] = pack_trunc(va.x, va.y);
            u.u[1] = pack_trunc(va.z, va.w);
            u.u[2] = pack_trunc(vb.x, vb.y);
            u.u[3] = pack_trunc(vb.z, vb.w);
            bf[t] = u.v;
        }
        #pragma unroll
        for (int mi = 0; mi < 4; ++mi)
            #pragma unroll
            for (int ni = 0; ni < 4; ++ni)
                acc[mi][ni] = __builtin_amdgcn_mfma_f32_16x16x32_bf16(
                    af[mi], bf[ni], acc[mi][ni], 0, 0, 0);

        par ^= 1;
    }

    // ---- dot partials: plain stores ----
    // C/D layout (16x16x32): col = lane&15, row = (lane>>4)*4 + reg
    float* outp = part + (size_t)bz * B * B;
    #pragma unroll
    for (int mi = 0; mi < 4; ++mi) {
        #pragma unroll
        for (int ni = 0; ni < 4; ++ni) {
            #pragma unroll
            for (int r = 0; r < 4; ++r) {
                const int ig = i0 + wm * 64 + mi * 16 + quad * 4 + r;
                const int jg = j0 + wn * 64 + ni * 16 + l15;
                if (ig < B && jg < B)
                    outp[(size_t)ig * B + jg] = acc[mi][ni][r];
            }
        }
    }

    // ---- norm partials: pair-reduce, one plain store per row ----
    if (doS) {
        float v = pns + __shfl_xor(pns, 1, 64);
        if (hn == 0 && i0 + rn < B) spart[(size_t)bz * B + i0 + rn] = v;
    }
    if (doT) {
        float v = pnt + __shfl_xor(pnt, 1, 64);
        if (hn == 0 && j0 + rn < B) tpart[(size_t)bz * B + j0 + rn] = v;
    }
}

// ---------------- tail: z-reduce + norms + topk + CE/KL, one kernel --------
// grid = B blocks; block i handles row i. Thread j reduces part[:,i,j] with
// unroll-8 pipelined loads. Last block to finish finalizes out[0..2].
__global__ __launch_bounds__(256) void tail_kernel(const float* __restrict__ part,
                                                   const float* __restrict__ spart,
                                                   const float* __restrict__ tpart,
                                                   const float* __restrict__ t_logits,
                                                   const float* __restrict__ s_logits,
                                                   const int* __restrict__ labels,
                                                   const int* __restrict__ kp,
                                                   const int* __restrict__ tp,
                                                   float* __restrict__ rowsum,
                                                   int* __restrict__ counter,
                                                   float* __restrict__ out,
                                                   int B, int K, int NL, int gz) {
    const int i   = blockIdx.x;
    const int tid = threadIdx.x;
    const size_t BB = (size_t)B * B;

    __shared__ float svals[256];
    __shared__ float rv[256];
    __shared__ int   ri[256];
    __shared__ float red[4];
    __shared__ float snv;
    __shared__ int   lastf;

    // ---- s_nrm_i: threads cooperate over z
    float sp = 0.f;
    for (int z = tid; z < gz; z += 256) sp += spart[(size_t)z * B + i];
    #pragma unroll
    for (int off = 32; off > 0; off >>= 1) sp += __shfl_down(sp, off, 64);
    if ((tid & 63) == 0) red[tid >> 6] = sp;
    __syncthreads();
    if (tid == 0) snv = red[0] + red[1] + red[2] + red[3];
    __syncthreads();
    const float sn = snv;

    // ---- dt_j, tn_j: unroll-8 z-reduction (pipelined independent loads)
    float v = INFINITY;
    if (tid < B) {
        const float* pp = part + (size_t)i * B + tid;
        const float* tq = tpart + tid;
        float d0=0.f,d1=0.f,d2=0.f,d3=0.f,d4=0.f,d5=0.f,d6=0.f,d7=0.f;
        float tn = 0.f;
        int z = 0;
        for (; z + 8 <= gz; z += 8) {
            d0 += pp[(size_t)(z+0) * BB];
            d1 += pp[(size_t)(z+1) * BB];
            d2 += pp[(size_t)(z+2) * BB];
            d3 += pp[(size_t)(z+3) * BB];
            d4 += pp[(size_t)(z+4) * BB];
            d5 += pp[(size_t)(z+5) * BB];
            d6 += pp[(size_t)(z+6) * BB];
            d7 += pp[(size_t)(z+7) * BB];
            tn += tq[(size_t)(z+0) * B] + tq[(size_t)(z+1) * B]
                + tq[(size_t)(z+2) * B] + tq[(size_t)(z+3) * B]
                + tq[(size_t)(z+4) * B] + tq[(size_t)(z+5) * B]
                + tq[(size_t)(z+6) * B] + tq[(size_t)(z+7) * B];
        }
        float dt = ((d0+d1)+(d2+d3)) + ((d4+d5)+(d6+d7));
        for (; z < gz; ++z) {
            dt += pp[(size_t)z * BB];
            tn += tq[(size_t)z * B];
        }
        if (labels[i] == labels[tid])
            v = fmaxf(sn + tn - 2.0f * dt, 0.0f);
    }
    svals[tid] = v;
    __syncthreads();

    // ---- top-k smallest via LDS tournament
    const int k = kp[0];
    float sum = 0.0f;
    for (int it = 0; it < k; ++it) {
        rv[tid] = svals[tid];
        ri[tid] = tid;
        __syncthreads();
        #pragma unroll
        for (int s = 128; s > 0; s >>= 1) {
            if (tid < s) {
                if (rv[tid + s] < rv[tid]) { rv[tid] = rv[tid + s]; ri[tid] = ri[tid + s]; }
            }
            __syncthreads();
        }
        if (tid == 0) {
            if (rv[0] < 3.0e38f) sum += rv[0];
            svals[ri[0]] = INFINITY;
        }
        __syncthreads();
    }

    if (tid == 0) {
        rowsum[i] = sum;
        __threadfence();
        lastf = (atomicAdd(counter, 1) == B - 1) ? 1 : 0;
    }
    __syncthreads();
    if (!lastf) return;

    // ---- last block: finalize all three losses ----
    __threadfence();
    const float Tv = (float)tp[0];
    float rs = (tid < B) ? rowsum[tid] : 0.f;
    float ce = 0.0f, kl = 0.0f;
    for (int s = tid; s < B; s += 256) {
        const float* sl = s_logits + (size_t)s * NL;
        const float* tl = t_logits + (size_t)s * NL;
        float mx = -INFINITY;
        for (int c = 0; c < NL; ++c) mx = fmaxf(mx, sl[c]);
        float se = 0.0f;
        for (int c = 0; c < NL; ++c) se += expf(sl[c] - mx);
        ce += logf(se) + mx - sl[labels[s]];

        float mxs = -INFINITY, mxt = -INFINITY;
        for (int c = 0; c < NL; ++c) {
            mxs = fmaxf(mxs, sl[c] / Tv);
            mxt = fmaxf(mxt, tl[c] / Tv);
        }
        float ses = 0.0f, set = 0.0f;
        for (int c = 0; c < NL; ++c) {
            ses += expf(sl[c] / Tv - mxs);
            set += expf(tl[c] / Tv - mxt);
        }
        float lses = logf(ses) + mxs;
        float lset = logf(set) + mxt;
        for (int c = 0; c < NL; ++c) {
            float lst = tl[c] / Tv - lset;
            float ls  = sl[c] / Tv - lses;
            kl += expf(lst) * (lst - ls);
        }
    }
    #pragma unroll
    for (int off = 32; off > 0; off >>= 1) {
        ce += __shfl_down(ce, off, 64);
        kl += __shfl_down(kl, off, 64);
        rs += __shfl_down(rs, off, 64);
    }
    __shared__ float wce[4], wkl[4], wrs[4];
    if ((tid & 63) == 0) { wce[tid >> 6] = ce; wkl[tid >> 6] = kl; wrs[tid >> 6] = rs; }
    __syncthreads();
    if (tid == 0) {
        out[0] = (wce[0] + wce[1] + wce[2] + wce[3]) / (float)B;
        out[1] = (wkl[0] + wkl[1] + wkl[2] + wkl[3]) / (float)B * Tv * Tv;
        out[2] = (wrs[0] + wrs[1] + wrs[2] + wrs[3]) / (float)K;
    }
}

// ---------------------------------------------------------------------------
extern "C" void kernel_launch(void* const* d_in, const int* in_sizes, int n_in,
                              void* d_out, int out_size, void* d_ws, size_t ws_size,
                              hipStream_t stream) {
    const float* t_logits = (const float*)d_in[0];
    const float* s_logits = (const float*)d_in[1];
    const float* t_feat   = (const float*)d_in[2];
    const float* s_feat   = (const float*)d_in[3];
    const int*   labels   = (const int*)d_in[4];
    const int*   kp       = (const int*)d_in[5];
    const int*   tp       = (const int*)d_in[6];
    float* out = (float*)d_out;

    const int B  = in_sizes[4];          // 256
    const int NL = in_sizes[0] / B;      // 2
    const int K  = in_sizes[2] / B;      // S*H = 98304
    const size_t BB = (size_t)B * B;

    // split-K: prefer gz=192 (3 blocks/CU over the grid); K % (gz*BKF) == 0
    // and all workspace buffers must fit in ws.
    const size_t avail = ws_size / 4;
    const int cands[] = {192, 256, 128, 96, 64, 48, 32, 24, 16, 12, 8, 6, 4, 3, 2, 1};
    int gz = 1;
    for (int ci = 0; ci < 16; ++ci) {
        const int g = cands[ci];
        if (K % (g * BKF) != 0) continue;
        const size_t need = (size_t)g * BB + 2 * (size_t)g * B + B + 1;
        if (need <= avail) { gz = g; break; }
    }
    const int KC = K / gz;

    float* ws      = (float*)d_ws;
    float* part    = ws;                          // gz * B*B
    float* spart   = part + (size_t)gz * BB;      // gz * B
    float* tpart   = spart + (size_t)gz * B;      // gz * B
    float* rowsum  = tpart + (size_t)gz * B;      // B
    int*   counter = (int*)(rowsum + B);          // 1

    dim3 grid((B + BM - 1) / BM, (B + BN - 1) / BN, gz);
    const size_t lds_bytes = 4 * STAGE * sizeof(float);   // 2 stages x (As|Bs)
    gemm_dot_kernel<<<grid, 256, lds_bytes, stream>>>(s_feat, t_feat, part,
                                                      spart, tpart, counter,
                                                      B, K, KC);

    tail_kernel<<<B, 256, 0, stream>>>(part, spart, tpart, t_logits, s_logits,
                                       labels, kp, tp, rowsum, counter, out,
                                       B, K, NL, gz);
}